// Round 1
// baseline (15289.145 us; speedup 1.0000x reference)
//
#include <hip/hip_runtime.h>
#include <hip/hip_bf16.h>
#include <math.h>

// Problem dims
#define Bsz  64
#define Hd   2048
#define G3   6144     // 3*H
#define MELn 130
#define CHn  12
#define RHYn 3
#define Tn   32

__device__ __forceinline__ float sigf(float x) { return 1.0f / (1.0f + expf(-x)); }

// ---------------------------------------------------------------------------
// prep: transpose z1/z2 -> [128][64], condition -> [T][CH][64], init feedback idx
// ---------------------------------------------------------------------------
__global__ void prep_misc(const float* __restrict__ z1, const float* __restrict__ z2,
                          const float* __restrict__ cond,
                          float* __restrict__ z1t, float* __restrict__ z2t,
                          float* __restrict__ cond_t, int* __restrict__ rhy_idx,
                          int* __restrict__ mel_idx)
{
    int idx = blockIdx.x * 256 + threadIdx.x;
    if (idx < 128 * Bsz) {
        int j = idx >> 6, b = idx & 63;
        z1t[idx] = z1[b * 128 + j];
        z2t[idx] = z2[b * 128 + j];
    }
    if (idx < Tn * CHn * Bsz) {
        int t = idx / (CHn * Bsz);
        int r = idx - t * CHn * Bsz;
        int j = r >> 6, b = r & 63;
        cond_t[idx] = cond[b * (Tn * CHn) + t * CHn + j];
    }
    if (idx < Bsz) { rhy_idx[idx] = RHYn - 1; mel_idx[idx] = MELn - 1; }
}

// ---------------------------------------------------------------------------
// h0 = tanh(z2 @ wi0.T + bi0), h1 = tanh(z1 @ wi1.T + bi1); output transposed [j][b]
// ---------------------------------------------------------------------------
__global__ __launch_bounds__(256) void init_h_k(
    const float* __restrict__ z1t, const float* __restrict__ z2t,
    const float* __restrict__ wi0, const float* __restrict__ bi0,
    const float* __restrict__ wi1, const float* __restrict__ bi1,
    float* __restrict__ h0_out, float* __restrict__ h1_out)
{
    int lane = threadIdx.x & 63, wave = threadIdx.x >> 6;
    int j = blockIdx.x * 4 + wave;
    int which = blockIdx.y;
    const float* zt = which ? z1t : z2t;
    const float* wi = which ? wi1 : wi0;
    const float* bi = which ? bi1 : bi0;
    float* outh = which ? h1_out : h0_out;
    const float4* w4 = (const float4*)(wi + (size_t)j * 128);
    float acc = 0.f;
#pragma unroll 8
    for (int i = 0; i < 32; i++) {
        float4 w = w4[i];
        int k = i * 4;
        acc = fmaf(zt[(k + 0) * 64 + lane], w.x, acc);
        acc = fmaf(zt[(k + 1) * 64 + lane], w.y, acc);
        acc = fmaf(zt[(k + 2) * 64 + lane], w.z, acc);
        acc = fmaf(zt[(k + 3) * 64 + lane], w.w, acc);
    }
    outh[j * 64 + lane] = tanhf(acc + bi[j]);
}

// ---------------------------------------------------------------------------
// step-invariant ih parts:
//   gi0c[row][b] = b_ih0[row] + sum_i z2[b,i]*w_ih0[row, 3+i]
//   gi1c[row][b] = b_ih1[row] + sum_i z1[b,i]*w_ih1[row, 133+i]
// ---------------------------------------------------------------------------
__global__ __launch_bounds__(256) void gi_const_k(
    const float* __restrict__ z1t, const float* __restrict__ z2t,
    const float* __restrict__ w_ih0, const float* __restrict__ b_ih0,
    const float* __restrict__ w_ih1, const float* __restrict__ b_ih1,
    float* __restrict__ gi0c, float* __restrict__ gi1c)
{
    int lane = threadIdx.x & 63, wave = threadIdx.x >> 6;
    int row = blockIdx.x * 4 + wave;
    int which = blockIdx.y;
    const float* zt; const float* w; float acc; float* dst;
    if (which == 0) { zt = z2t; w = w_ih0 + (size_t)row * 131 + RHYn;         acc = b_ih0[row]; dst = gi0c; }
    else            { zt = z1t; w = w_ih1 + (size_t)row * 273 + (MELn + RHYn); acc = b_ih1[row]; dst = gi1c; }
#pragma unroll 4
    for (int i = 0; i < 128; i++) acc = fmaf(zt[i * 64 + lane], w[i], acc);
    dst[(size_t)row * 64 + lane] = acc;
}

// ---------------------------------------------------------------------------
// rhythm GRU step: h' = GRU(concat(onehot(oi), z2), h)  [ih part precomputed]
// grid 256, block 512: wave -> hidden unit j; lane = batch
// ---------------------------------------------------------------------------
__global__ __launch_bounds__(512) void gru_rhy_step(
    const float* __restrict__ h_in, float* __restrict__ h_out,
    const float* __restrict__ w_hh, const float* __restrict__ b_hh,
    const float* __restrict__ w_ih, const float* __restrict__ gi_c,
    const int* __restrict__ fb_idx)
{
    __shared__ float hsm[128 * 64];
    int tid = threadIdx.x;
    int lane = tid & 63, wave = tid >> 6;
    int j = blockIdx.x * 8 + wave;
    const float* wr = w_hh + (size_t)j * Hd;
    const float* wz = w_hh + (size_t)(j + Hd) * Hd;
    const float* wn = w_hh + (size_t)(j + 2 * Hd) * Hd;
    float ar = 0.f, az = 0.f, an = 0.f;
    for (int c = 0; c < Hd; c += 128) {
        __syncthreads();
        const float4* src = (const float4*)(h_in + c * 64);
        float4* dst4 = (float4*)hsm;
#pragma unroll
        for (int i = 0; i < 4; i++) dst4[tid + i * 512] = src[tid + i * 512];
        __syncthreads();
#pragma unroll 4
        for (int kk = 0; kk < 128; kk += 4) {
            float4 w4r = *(const float4*)(wr + c + kk);
            float4 w4z = *(const float4*)(wz + c + kk);
            float4 w4n = *(const float4*)(wn + c + kk);
            float h0 = hsm[(kk + 0) * 64 + lane];
            float h1 = hsm[(kk + 1) * 64 + lane];
            float h2 = hsm[(kk + 2) * 64 + lane];
            float h3 = hsm[(kk + 3) * 64 + lane];
            ar = fmaf(h0, w4r.x, ar); ar = fmaf(h1, w4r.y, ar); ar = fmaf(h2, w4r.z, ar); ar = fmaf(h3, w4r.w, ar);
            az = fmaf(h0, w4z.x, az); az = fmaf(h1, w4z.y, az); az = fmaf(h2, w4z.z, az); az = fmaf(h3, w4z.w, az);
            an = fmaf(h0, w4n.x, an); an = fmaf(h1, w4n.y, an); an = fmaf(h2, w4n.z, an); an = fmaf(h3, w4n.w, an);
        }
    }
    int oi = fb_idx[lane];
    float gir = gi_c[(size_t)j * 64 + lane]            + w_ih[(size_t)j * 131 + oi];
    float giz = gi_c[(size_t)(j + Hd) * 64 + lane]     + w_ih[(size_t)(j + Hd) * 131 + oi];
    float gin = gi_c[(size_t)(j + 2 * Hd) * 64 + lane] + w_ih[(size_t)(j + 2 * Hd) * 131 + oi];
    float rg = sigf(gir + ar + b_hh[j]);
    float ug = sigf(giz + az + b_hh[j + Hd]);
    float ng = tanhf(gin + rg * (an + b_hh[j + 2 * Hd]));
    float hp = h_in[(size_t)j * 64 + lane];
    h_out[(size_t)j * 64 + lane] = (1.f - ug) * ng + ug * hp;
}

// ---------------------------------------------------------------------------
// rhythm logits (3 classes) + log_softmax + argmax -> feedback idx
// single block, 1024 threads: 12 waves = 3 classes x 4 K-chunks
// ---------------------------------------------------------------------------
__global__ __launch_bounds__(1024) void rhy_logits_k(
    const float* __restrict__ h, const float* __restrict__ wo0,
    const float* __restrict__ bo0, float* __restrict__ rlo, int* __restrict__ rhy_idx)
{
    __shared__ float part[12 * 64];
    int tid = threadIdx.x, lane = tid & 63, wave = tid >> 6;
    if (wave < 12) {
        int c = wave >> 2, chunk = wave & 3;
        const float* w = wo0 + c * Hd + chunk * 512;
        const float* hc = h + chunk * 512 * 64;
        float acc = 0.f;
#pragma unroll 4
        for (int k = 0; k < 512; k++) acc = fmaf(hc[k * 64 + lane], w[k], acc);
        part[wave * 64 + lane] = acc;
    }
    __syncthreads();
    if (wave == 0) {
        float l0 = part[0 * 64 + lane] + part[1 * 64 + lane] + part[2 * 64 + lane] + part[3 * 64 + lane] + bo0[0];
        float l1 = part[4 * 64 + lane] + part[5 * 64 + lane] + part[6 * 64 + lane] + part[7 * 64 + lane] + bo0[1];
        float l2 = part[8 * 64 + lane] + part[9 * 64 + lane] + part[10 * 64 + lane] + part[11 * 64 + lane] + bo0[2];
        int am; float mx;
        if (l0 >= l1 && l0 >= l2) { am = 0; mx = l0; }
        else if (l1 >= l2)        { am = 1; mx = l1; }
        else                      { am = 2; mx = l2; }
        float s = expf(l0 - mx) + expf(l1 - mx) + expf(l2 - mx);
        float ls = logf(s);
        rlo[lane * 3 + 0] = l0 - mx - ls;
        rlo[lane * 3 + 1] = l1 - mx - ls;
        rlo[lane * 3 + 2] = l2 - mx - ls;
        rhy_idx[lane] = am;
    }
}

// ---------------------------------------------------------------------------
// melody GRU1: ha' = GRU(concat(onehot(mel), r_t, z1, c_t), ha)
// ---------------------------------------------------------------------------
__global__ __launch_bounds__(512) void gru_mel1_step(
    const float* __restrict__ ha_in, float* __restrict__ ha_out,
    const float* __restrict__ w_hh, const float* __restrict__ b_hh,
    const float* __restrict__ w_ih, const float* __restrict__ gi_c,
    const int* __restrict__ mel_idx, const float* __restrict__ rlo,
    const float* __restrict__ cdt)
{
    __shared__ float hsm[128 * 64];
    int tid = threadIdx.x;
    int lane = tid & 63, wave = tid >> 6;
    int j = blockIdx.x * 8 + wave;
    const float* wr = w_hh + (size_t)j * Hd;
    const float* wz = w_hh + (size_t)(j + Hd) * Hd;
    const float* wn = w_hh + (size_t)(j + 2 * Hd) * Hd;
    float ar = 0.f, az = 0.f, an = 0.f;
    for (int c = 0; c < Hd; c += 128) {
        __syncthreads();
        const float4* src = (const float4*)(ha_in + c * 64);
        float4* dst4 = (float4*)hsm;
#pragma unroll
        for (int i = 0; i < 4; i++) dst4[tid + i * 512] = src[tid + i * 512];
        __syncthreads();
#pragma unroll 4
        for (int kk = 0; kk < 128; kk += 4) {
            float4 w4r = *(const float4*)(wr + c + kk);
            float4 w4z = *(const float4*)(wz + c + kk);
            float4 w4n = *(const float4*)(wn + c + kk);
            float h0 = hsm[(kk + 0) * 64 + lane];
            float h1 = hsm[(kk + 1) * 64 + lane];
            float h2 = hsm[(kk + 2) * 64 + lane];
            float h3 = hsm[(kk + 3) * 64 + lane];
            ar = fmaf(h0, w4r.x, ar); ar = fmaf(h1, w4r.y, ar); ar = fmaf(h2, w4r.z, ar); ar = fmaf(h3, w4r.w, ar);
            az = fmaf(h0, w4z.x, az); az = fmaf(h1, w4z.y, az); az = fmaf(h2, w4z.z, az); az = fmaf(h3, w4z.w, az);
            an = fmaf(h0, w4n.x, an); an = fmaf(h1, w4n.y, an); an = fmaf(h2, w4n.z, an); an = fmaf(h3, w4n.w, an);
        }
    }
    int oi = mel_idx[lane];
    float r0 = rlo[lane * 3 + 0], r1 = rlo[lane * 3 + 1], r2 = rlo[lane * 3 + 2];
    float cd[12];
#pragma unroll
    for (int q = 0; q < 12; q++) cd[q] = cdt[q * 64 + lane];
    float gi[3];
#pragma unroll
    for (int g = 0; g < 3; g++) {
        size_t row = (size_t)j + (size_t)g * Hd;
        const float* wrow = w_ih + row * 273;
        float v = gi_c[row * 64 + lane] + wrow[oi];
        v = fmaf(r0, wrow[130], v);
        v = fmaf(r1, wrow[131], v);
        v = fmaf(r2, wrow[132], v);
#pragma unroll
        for (int q = 0; q < 12; q++) v = fmaf(cd[q], wrow[261 + q], v);
        gi[g] = v;
    }
    float rg = sigf(gi[0] + ar + b_hh[j]);
    float ug = sigf(gi[1] + az + b_hh[j + Hd]);
    float ng = tanhf(gi[2] + rg * (an + b_hh[j + 2 * Hd]));
    float hp = ha_in[(size_t)j * 64 + lane];
    ha_out[(size_t)j * 64 + lane] = (1.f - ug) * ng + ug * hp;
}

// ---------------------------------------------------------------------------
// melody GRU2: hb' = GRU(x=ha', h=hb_eff) — two dense K=2048 matmuls
// ---------------------------------------------------------------------------
__global__ __launch_bounds__(512) void gru_mel2_step(
    const float* __restrict__ x_in, const float* __restrict__ hb_in, float* __restrict__ hb_out,
    const float* __restrict__ w_ih, const float* __restrict__ b_ih,
    const float* __restrict__ w_hh, const float* __restrict__ b_hh)
{
    __shared__ float xsm[128 * 64];
    __shared__ float hsm[128 * 64];
    int tid = threadIdx.x;
    int lane = tid & 63, wave = tid >> 6;
    int j = blockIdx.x * 8 + wave;
    const float* wir = w_ih + (size_t)j * Hd;
    const float* wiz = w_ih + (size_t)(j + Hd) * Hd;
    const float* win = w_ih + (size_t)(j + 2 * Hd) * Hd;
    const float* whr = w_hh + (size_t)j * Hd;
    const float* whz = w_hh + (size_t)(j + Hd) * Hd;
    const float* whn = w_hh + (size_t)(j + 2 * Hd) * Hd;
    float air = 0.f, aiz = 0.f, ain = 0.f, ahr = 0.f, ahz = 0.f, ahn = 0.f;
    for (int c = 0; c < Hd; c += 128) {
        __syncthreads();
        const float4* sx = (const float4*)(x_in + c * 64);
        const float4* sh = (const float4*)(hb_in + c * 64);
        float4* dx = (float4*)xsm;
        float4* dh = (float4*)hsm;
#pragma unroll
        for (int i = 0; i < 4; i++) { dx[tid + i * 512] = sx[tid + i * 512]; dh[tid + i * 512] = sh[tid + i * 512]; }
        __syncthreads();
#pragma unroll 2
        for (int kk = 0; kk < 128; kk += 4) {
            float4 a4 = *(const float4*)(wir + c + kk);
            float4 b4 = *(const float4*)(wiz + c + kk);
            float4 c4 = *(const float4*)(win + c + kk);
            float4 d4 = *(const float4*)(whr + c + kk);
            float4 e4 = *(const float4*)(whz + c + kk);
            float4 f4 = *(const float4*)(whn + c + kk);
            float x0 = xsm[(kk + 0) * 64 + lane];
            float x1 = xsm[(kk + 1) * 64 + lane];
            float x2 = xsm[(kk + 2) * 64 + lane];
            float x3 = xsm[(kk + 3) * 64 + lane];
            float h0 = hsm[(kk + 0) * 64 + lane];
            float h1 = hsm[(kk + 1) * 64 + lane];
            float h2 = hsm[(kk + 2) * 64 + lane];
            float h3 = hsm[(kk + 3) * 64 + lane];
            air = fmaf(x0, a4.x, air); air = fmaf(x1, a4.y, air); air = fmaf(x2, a4.z, air); air = fmaf(x3, a4.w, air);
            aiz = fmaf(x0, b4.x, aiz); aiz = fmaf(x1, b4.y, aiz); aiz = fmaf(x2, b4.z, aiz); aiz = fmaf(x3, b4.w, aiz);
            ain = fmaf(x0, c4.x, ain); ain = fmaf(x1, c4.y, ain); ain = fmaf(x2, c4.z, ain); ain = fmaf(x3, c4.w, ain);
            ahr = fmaf(h0, d4.x, ahr); ahr = fmaf(h1, d4.y, ahr); ahr = fmaf(h2, d4.z, ahr); ahr = fmaf(h3, d4.w, ahr);
            ahz = fmaf(h0, e4.x, ahz); ahz = fmaf(h1, e4.y, ahz); ahz = fmaf(h2, e4.z, ahz); ahz = fmaf(h3, e4.w, ahz);
            ahn = fmaf(h0, f4.x, ahn); ahn = fmaf(h1, f4.y, ahn); ahn = fmaf(h2, f4.z, ahn); ahn = fmaf(h3, f4.w, ahn);
        }
    }
    float rg = sigf(air + b_ih[j] + ahr + b_hh[j]);
    float ug = sigf(aiz + b_ih[j + Hd] + ahz + b_hh[j + Hd]);
    float ng = tanhf(ain + b_ih[j + 2 * Hd] + rg * (ahn + b_hh[j + 2 * Hd]));
    float hp = hb_in[(size_t)j * 64 + lane];
    hb_out[(size_t)j * 64 + lane] = (1.f - ug) * ng + ug * hp;
}

// ---------------------------------------------------------------------------
// melody logits: one block per class; 4 waves split K
// ---------------------------------------------------------------------------
__global__ __launch_bounds__(256) void logits_mel_k(
    const float* __restrict__ h, const float* __restrict__ wo1,
    const float* __restrict__ bo1, float* __restrict__ logits)
{
    __shared__ float part[4 * 64];
    int tid = threadIdx.x, lane = tid & 63, wave = tid >> 6;
    int cls = blockIdx.x;
    const float* w = wo1 + (size_t)cls * Hd + wave * 512;
    const float* hc = h + wave * 512 * 64;
    float acc = 0.f;
#pragma unroll 4
    for (int k = 0; k < 512; k++) acc = fmaf(hc[k * 64 + lane], w[k], acc);
    part[wave * 64 + lane] = acc;
    __syncthreads();
    if (wave == 0)
        logits[cls * 64 + lane] = part[0 * 64 + lane] + part[1 * 64 + lane] +
                                  part[2 * 64 + lane] + part[3 * 64 + lane] + bo1[cls];
}

// ---------------------------------------------------------------------------
// melody log_softmax + argmax + output write; one block per batch row
// ---------------------------------------------------------------------------
__global__ __launch_bounds__(256) void softmax_mel_k(
    const float* __restrict__ logits, float* __restrict__ outp, int t, int* __restrict__ mel_idx)
{
    int b = blockIdx.x, tid = threadIdx.x;
    float v = (tid < MELn) ? logits[tid * 64 + b] : -1e30f;
    __shared__ float smax[256];
    __shared__ int   sidx[256];
    __shared__ float ssum[256];
    smax[tid] = v; sidx[tid] = tid;
    __syncthreads();
    for (int s = 128; s > 0; s >>= 1) {
        if (tid < s) {
            float a = smax[tid], o = smax[tid + s];
            int ai = sidx[tid], oi = sidx[tid + s];
            if (o > a || (o == a && oi < ai)) { smax[tid] = o; sidx[tid] = oi; }
        }
        __syncthreads();
    }
    float mx = smax[0]; int am = sidx[0];
    ssum[tid] = (tid < MELn) ? expf(v - mx) : 0.f;
    __syncthreads();
    for (int s = 128; s > 0; s >>= 1) {
        if (tid < s) ssum[tid] += ssum[tid + s];
        __syncthreads();
    }
    float ls = logf(ssum[0]);
    if (tid < MELn) outp[(size_t)b * Tn * MELn + t * MELn + tid] = v - mx - ls;
    if (tid == 0) mel_idx[b] = am;
}

// ---------------------------------------------------------------------------
extern "C" void kernel_launch(void* const* d_in, const int* in_sizes, int n_in,
                              void* d_out, int out_size, void* d_ws, size_t ws_size,
                              hipStream_t stream)
{
    (void)in_sizes; (void)n_in; (void)out_size; (void)ws_size;
    const float* z1    = (const float*)d_in[0];
    const float* z2    = (const float*)d_in[1];
    const float* cond  = (const float*)d_in[2];
    const float* w_ih0 = (const float*)d_in[3];
    const float* w_hh0 = (const float*)d_in[4];
    const float* b_ih0 = (const float*)d_in[5];
    const float* b_hh0 = (const float*)d_in[6];
    const float* w_ih1 = (const float*)d_in[7];
    const float* w_hh1 = (const float*)d_in[8];
    const float* b_ih1 = (const float*)d_in[9];
    const float* b_hh1 = (const float*)d_in[10];
    const float* w_ih2 = (const float*)d_in[11];
    const float* w_hh2 = (const float*)d_in[12];
    const float* b_ih2 = (const float*)d_in[13];
    const float* b_hh2 = (const float*)d_in[14];
    const float* wi0   = (const float*)d_in[15];
    const float* bi0   = (const float*)d_in[16];
    const float* wo0   = (const float*)d_in[17];
    const float* bo0   = (const float*)d_in[18];
    const float* wi1   = (const float*)d_in[19];
    const float* bi1   = (const float*)d_in[20];
    const float* wo1   = (const float*)d_in[21];
    const float* bo1   = (const float*)d_in[22];
    float* outp = (float*)d_out;
    float* ws = (float*)d_ws;

    // workspace layout (floats); total 1,628,416 floats ~= 6.3 MB
    float* hR[2] = { ws,            ws + 131072 };
    float* hA[2] = { ws + 262144,   ws + 393216 };
    float* hB[2] = { ws + 524288,   ws + 655360 };
    float* gi0c   = ws + 786432;    // [6144][64]
    float* gi1c   = ws + 1179648;   // [6144][64]
    float* rhy_lo = ws + 1572864;   // [32][64][3]
    float* cond_t = ws + 1579008;   // [32][12][64]
    float* z1t    = ws + 1603584;   // [128][64]
    float* z2t    = ws + 1611776;   // [128][64]
    float* logits = ws + 1619968;   // [130][64]
    int* rhy_idx  = (int*)(ws + 1628288);
    int* mel_idx  = (int*)(ws + 1628352);

    prep_misc<<<96, 256, 0, stream>>>(z1, z2, cond, z1t, z2t, cond_t, rhy_idx, mel_idx);
    init_h_k<<<dim3(Hd / 4, 2), 256, 0, stream>>>(z1t, z2t, wi0, bi0, wi1, bi1, hR[0], hA[0]);
    gi_const_k<<<dim3(G3 / 4, 2), 256, 0, stream>>>(z1t, z2t, w_ih0, b_ih0, w_ih1, b_ih1, gi0c, gi1c);

    // rhythm decoder
    for (int s = 0; s < Tn; s++) {
        gru_rhy_step<<<Hd / 8, 512, 0, stream>>>(hR[s & 1], hR[(s + 1) & 1],
                                                 w_hh0, b_hh0, w_ih0, gi0c, rhy_idx);
        rhy_logits_k<<<1, 1024, 0, stream>>>(hR[(s + 1) & 1], wo0, bo0,
                                             rhy_lo + s * (Bsz * RHYn), rhy_idx);
    }
    // melody decoder
    for (int t = 0; t < Tn; t++) {
        const float* ha_in = hA[t & 1];
        float* ha_out = hA[(t + 1) & 1];
        gru_mel1_step<<<Hd / 8, 512, 0, stream>>>(ha_in, ha_out, w_hh1, b_hh1, w_ih1, gi1c,
                                                  mel_idx, rhy_lo + t * (Bsz * RHYn),
                                                  cond_t + t * (CHn * Bsz));
        const float* hb_in = (t == 0) ? (const float*)ha_out : (const float*)hB[t & 1];
        float* hb_out = hB[(t + 1) & 1];
        gru_mel2_step<<<Hd / 8, 512, 0, stream>>>(ha_out, hb_in, hb_out,
                                                  w_ih2, b_ih2, w_hh2, b_hh2);
        logits_mel_k<<<MELn, 256, 0, stream>>>(hb_out, wo1, bo1, logits);
        softmax_mel_k<<<Bsz, 256, 0, stream>>>(logits, outp, t, mel_idx);
    }
}

// Round 2
// 11810.217 us; speedup vs baseline: 1.2946x; 1.2946x over previous
//
#include <hip/hip_runtime.h>
#include <hip/hip_bf16.h>
#include <math.h>

#define Bsz  64
#define Hd   2048
#define G3   6144
#define MELn 130
#define CHn  12
#define RHYn 3
#define Tn   32

__device__ __forceinline__ float sigf(float x) { return 1.0f / (1.0f + expf(-x)); }

// ---------------------------------------------------------------------------
// prep: transpose z1/z2 -> [128][64], condition -> [T][CH][64], init feedback idx
// ---------------------------------------------------------------------------
__global__ void prep_misc(const float* __restrict__ z1, const float* __restrict__ z2,
                          const float* __restrict__ cond,
                          float* __restrict__ z1t, float* __restrict__ z2t,
                          float* __restrict__ cond_t, int* __restrict__ rhy_idx,
                          int* __restrict__ mel_idx)
{
    int idx = blockIdx.x * 256 + threadIdx.x;
    if (idx < 128 * Bsz) {
        int j = idx >> 6, b = idx & 63;
        z1t[idx] = z1[b * 128 + j];
        z2t[idx] = z2[b * 128 + j];
    }
    if (idx < Tn * CHn * Bsz) {
        int t = idx / (CHn * Bsz);
        int r = idx - t * CHn * Bsz;
        int j = r >> 6, b = r & 63;
        cond_t[idx] = cond[b * (Tn * CHn) + t * CHn + j];
    }
    if (idx < Bsz) { rhy_idx[idx] = RHYn - 1; mel_idx[idx] = MELn - 1; }
}

// ---------------------------------------------------------------------------
// h0 = tanh(z2 @ wi0.T + bi0), h1 = tanh(z1 @ wi1.T + bi1); output [j][b]
// ---------------------------------------------------------------------------
__global__ __launch_bounds__(256) void init_h_k(
    const float* __restrict__ z1t, const float* __restrict__ z2t,
    const float* __restrict__ wi0, const float* __restrict__ bi0,
    const float* __restrict__ wi1, const float* __restrict__ bi1,
    float* __restrict__ h0_out, float* __restrict__ h1_out)
{
    int lane = threadIdx.x & 63, wave = threadIdx.x >> 6;
    int j = blockIdx.x * 4 + wave;
    int which = blockIdx.y;
    const float* zt = which ? z1t : z2t;
    const float* wi = which ? wi1 : wi0;
    const float* bi = which ? bi1 : bi0;
    float* outh = which ? h1_out : h0_out;
    const float4* w4 = (const float4*)(wi + (size_t)j * 128);
    float acc = 0.f;
#pragma unroll 8
    for (int i = 0; i < 32; i++) {
        float4 w = w4[i];
        int k = i * 4;
        acc = fmaf(zt[(k + 0) * 64 + lane], w.x, acc);
        acc = fmaf(zt[(k + 1) * 64 + lane], w.y, acc);
        acc = fmaf(zt[(k + 2) * 64 + lane], w.z, acc);
        acc = fmaf(zt[(k + 3) * 64 + lane], w.w, acc);
    }
    outh[j * 64 + lane] = tanhf(acc + bi[j]);
}

// ---------------------------------------------------------------------------
// step-invariant ih parts (z-terms + bias), layout [row][64]
// ---------------------------------------------------------------------------
__global__ __launch_bounds__(256) void gi_const_k(
    const float* __restrict__ z1t, const float* __restrict__ z2t,
    const float* __restrict__ w_ih0, const float* __restrict__ b_ih0,
    const float* __restrict__ w_ih1, const float* __restrict__ b_ih1,
    float* __restrict__ gi0c, float* __restrict__ gi1c)
{
    int lane = threadIdx.x & 63, wave = threadIdx.x >> 6;
    int row = blockIdx.x * 4 + wave;
    int which = blockIdx.y;
    const float* zt; const float* w; float acc; float* dst;
    if (which == 0) { zt = z2t; w = w_ih0 + (size_t)row * 131 + RHYn;          acc = b_ih0[row]; dst = gi0c; }
    else            { zt = z1t; w = w_ih1 + (size_t)row * 273 + (MELn + RHYn); acc = b_ih1[row]; dst = gi1c; }
#pragma unroll 4
    for (int i = 0; i < 128; i++) acc = fmaf(zt[i * 64 + lane], w[i], acc);
    dst[(size_t)row * 64 + lane] = acc;
}

// ---------------------------------------------------------------------------
// 64x64 tile transpose: in [R][C] -> out [C][R]
// ---------------------------------------------------------------------------
__device__ __forceinline__ void transpose_body(
    const float* __restrict__ in, float* __restrict__ out, int R, int C,
    int bx, int by, float* tile)
{
    int c0 = bx * 64, r0 = by * 64;
    int t = threadIdx.x;
    int cl = t & 63, rw = t >> 6;
#pragma unroll
    for (int i = 0; i < 16; ++i) {
        int rl = rw + i * 4;
        int r = r0 + rl, c = c0 + cl;
        float v = (r < R && c < C) ? in[(size_t)r * C + c] : 0.f;
        tile[rl * 65 + cl] = v;
    }
    __syncthreads();
#pragma unroll
    for (int i = 0; i < 16; ++i) {
        int c_loc = rw + i * 4;
        int r_loc = cl;
        int oc = c0 + c_loc, orow = r0 + r_loc;
        if (oc < C && orow < R)
            out[(size_t)oc * R + orow] = tile[r_loc * 65 + c_loc];
    }
}

__global__ __launch_bounds__(256) void transpose4_k(
    const float* __restrict__ a, const float* __restrict__ b,
    const float* __restrict__ c, const float* __restrict__ d,
    float* __restrict__ oa, float* __restrict__ ob,
    float* __restrict__ oc, float* __restrict__ od)
{
    __shared__ float tile[64 * 65];
    const float* in; float* out;
    switch (blockIdx.z) {
        case 0: in = a; out = oa; break;
        case 1: in = b; out = ob; break;
        case 2: in = c; out = oc; break;
        default: in = d; out = od; break;
    }
    transpose_body(in, out, G3, Hd, blockIdx.x, blockIdx.y, tile);
}

__global__ __launch_bounds__(256) void transpose1_k(
    const float* __restrict__ in, float* __restrict__ out, int R, int C)
{
    __shared__ float tile[64 * 65];
    transpose_body(in, out, R, C, blockIdx.x, blockIdx.y, tile);
}

// ---------------------------------------------------------------------------
// mm_k: part[slot][grow][boff+b] = sum_{k in slot chunk} WT[k][row] * x[k][b]
// block = 128 threads (lane -> row, 128 rows/block); grid (tiles128, S, 2)
// Uniformity: k-slot and b-half come from blockIdx => h reads are s_loads.
// Fused two-matrix mode: blocks >= splitTile use (WTb, xb).
// ---------------------------------------------------------------------------
__global__ __launch_bounds__(128) void mm_k(
    const float* __restrict__ WTa, const float* __restrict__ xa,
    const float* __restrict__ WTb, const float* __restrict__ xb,
    float* __restrict__ part, int nrows_a, int nrows_b, int splitTile,
    int kc, int slotStride)
{
    __shared__ float buf[128 * 33];
    int tid = threadIdx.x;
    int tile = blockIdx.x, slot = blockIdx.y, bh = blockIdx.z;
    const float* WT; const float* hin; int nrows; int row;
    if (tile < splitTile) { WT = WTa; hin = xa; nrows = nrows_a; row = tile * 128 + tid; }
    else { WT = WTb; hin = xb; nrows = nrows_b; row = (tile - splitTile) * 128 + tid; }
    int rowc = row < nrows ? row : (nrows - 1);
    int k0 = slot * kc;
    int boff = bh * 32;

    float acc[32];
#pragma unroll
    for (int b = 0; b < 32; b++) acc[b] = 0.f;

    for (int k = k0; k < k0 + kc; ++k) {
        float wv = WT[(size_t)k * nrows + rowc];         // coalesced per-lane
        const float* hr = hin + k * 64 + boff;           // uniform -> s_load
#pragma unroll
        for (int b = 0; b < 32; b++) acc[b] = fmaf(hr[b], wv, acc[b]);
    }

    // LDS transpose: buf[row_loc][b], pad 33 (conflict-free)
#pragma unroll
    for (int b = 0; b < 32; b++) buf[tid * 33 + b] = acc[b];
    __syncthreads();

    // coalesced store: thread -> (b, row-quarter)
    int b_l = tid & 31, rq = tid >> 5;  // rq 0..3
    size_t base = (size_t)slot * slotStride + boff + b_l;
#pragma unroll 4
    for (int r2 = 0; r2 < 32; ++r2) {
        int r = r2 * 4 + rq;
        int grow = tile * 128 + r;
        part[base + (size_t)grow * 64] = buf[r * 33 + b_l];
    }
}

// ---------------------------------------------------------------------------
// rhythm epilogue: sum 16 k-slots, gate math, h'
// ---------------------------------------------------------------------------
__global__ __launch_bounds__(256) void rhy_epi(
    const float* __restrict__ part, const float* __restrict__ gi_c,
    const float* __restrict__ w_ih, const float* __restrict__ b_hh,
    const float* __restrict__ h_in, float* __restrict__ h_out,
    const int* __restrict__ fb_idx)
{
    int tid = threadIdx.x;
    int b = tid & 63, jw = tid >> 6;
    int j = blockIdx.x * 4 + jw;
    float ar = 0.f, az = 0.f, an = 0.f;
#pragma unroll
    for (int s = 0; s < 16; s++) {
        int sb = s * 393216;
        ar += part[sb + j * 64 + b];
        az += part[sb + (j + 2048) * 64 + b];
        an += part[sb + (j + 4096) * 64 + b];
    }
    int oi = fb_idx[b];
    float gir = gi_c[j * 64 + b]            + w_ih[(size_t)j * 131 + oi];
    float giz = gi_c[(j + 2048) * 64 + b]   + w_ih[(size_t)(j + 2048) * 131 + oi];
    float gin = gi_c[(j + 4096) * 64 + b]   + w_ih[(size_t)(j + 4096) * 131 + oi];
    float rg = sigf(gir + ar + b_hh[j]);
    float ug = sigf(giz + az + b_hh[j + 2048]);
    float ng = tanhf(gin + rg * (an + b_hh[j + 4096]));
    float hp = h_in[j * 64 + b];
    h_out[j * 64 + b] = (1.f - ug) * ng + ug * hp;
}

// ---------------------------------------------------------------------------
// melody GRU1 epilogue: sum 16 slots + one-hot col + rank-15 corrections
// ---------------------------------------------------------------------------
__global__ __launch_bounds__(256) void mel1_epi(
    const float* __restrict__ part, const float* __restrict__ gi_c,
    const float* __restrict__ w_ih, const float* __restrict__ b_hh,
    const float* __restrict__ h_in, float* __restrict__ h_out,
    const int* __restrict__ mel_idx, const float* __restrict__ rlo,
    const float* __restrict__ cdt)
{
    int tid = threadIdx.x;
    int b = tid & 63, jw = tid >> 6;
    int j = blockIdx.x * 4 + jw;
    float ar = 0.f, az = 0.f, an = 0.f;
#pragma unroll
    for (int s = 0; s < 16; s++) {
        int sb = s * 393216;
        ar += part[sb + j * 64 + b];
        az += part[sb + (j + 2048) * 64 + b];
        an += part[sb + (j + 4096) * 64 + b];
    }
    int oi = mel_idx[b];
    float r0 = rlo[b * 3 + 0], r1 = rlo[b * 3 + 1], r2 = rlo[b * 3 + 2];
    float cd[12];
#pragma unroll
    for (int q = 0; q < 12; q++) cd[q] = cdt[q * 64 + b];
    float gi[3];
#pragma unroll
    for (int g = 0; g < 3; g++) {
        int row = j + g * 2048;
        const float* wrow = w_ih + (size_t)row * 273;
        float v = gi_c[row * 64 + b] + wrow[oi];
        v = fmaf(r0, wrow[130], v);
        v = fmaf(r1, wrow[131], v);
        v = fmaf(r2, wrow[132], v);
#pragma unroll
        for (int q = 0; q < 12; q++) v = fmaf(cd[q], wrow[261 + q], v);
        gi[g] = v;
    }
    float rg = sigf(gi[0] + ar + b_hh[j]);
    float ug = sigf(gi[1] + az + b_hh[j + 2048]);
    float ng = tanhf(gi[2] + rg * (an + b_hh[j + 4096]));
    float hp = h_in[j * 64 + b];
    h_out[j * 64 + b] = (1.f - ug) * ng + ug * hp;
}

// ---------------------------------------------------------------------------
// melody GRU2 epilogue: fused rows [0,6144)=gi (ih2 x ha'), [6144,12288)=gh
// ---------------------------------------------------------------------------
__global__ __launch_bounds__(256) void mel2_epi(
    const float* __restrict__ part, const float* __restrict__ b_ih,
    const float* __restrict__ b_hh, const float* __restrict__ hb_in,
    float* __restrict__ hb_out)
{
    int tid = threadIdx.x;
    int b = tid & 63, jw = tid >> 6;
    int j = blockIdx.x * 4 + jw;
    float air = 0.f, aiz = 0.f, ain = 0.f, ahr = 0.f, ahz = 0.f, ahn = 0.f;
#pragma unroll
    for (int s = 0; s < 8; s++) {
        int sb = s * 786432;
        air += part[sb + j * 64 + b];
        aiz += part[sb + (j + 2048) * 64 + b];
        ain += part[sb + (j + 4096) * 64 + b];
        ahr += part[sb + (j + 6144) * 64 + b];
        ahz += part[sb + (j + 8192) * 64 + b];
        ahn += part[sb + (j + 10240) * 64 + b];
    }
    float rg = sigf(air + b_ih[j] + ahr + b_hh[j]);
    float ug = sigf(aiz + b_ih[j + 2048] + ahz + b_hh[j + 2048]);
    float ng = tanhf(ain + b_ih[j + 4096] + rg * (ahn + b_hh[j + 4096]));
    float hp = hb_in[j * 64 + b];
    hb_out[j * 64 + b] = (1.f - ug) * ng + ug * hp;
}

// ---------------------------------------------------------------------------
// rhythm softmax: 3 classes from 8 partial slots (stride 8192)
// ---------------------------------------------------------------------------
__global__ __launch_bounds__(64) void rhy_smax(
    const float* __restrict__ part, const float* __restrict__ bo0,
    float* __restrict__ rlo_t, int* __restrict__ rhy_idx)
{
    int b = threadIdx.x;
    float l[3];
#pragma unroll
    for (int c = 0; c < 3; c++) {
        float v = bo0[c];
#pragma unroll
        for (int s = 0; s < 8; s++) v += part[s * 8192 + c * 64 + b];
        l[c] = v;
    }
    int am; float mx;
    if (l[0] >= l[1] && l[0] >= l[2]) { am = 0; mx = l[0]; }
    else if (l[1] >= l[2])            { am = 1; mx = l[1]; }
    else                              { am = 2; mx = l[2]; }
    float s = expf(l[0] - mx) + expf(l[1] - mx) + expf(l[2] - mx);
    float ls = logf(s);
    rlo_t[b * 3 + 0] = l[0] - mx - ls;
    rlo_t[b * 3 + 1] = l[1] - mx - ls;
    rlo_t[b * 3 + 2] = l[2] - mx - ls;
    rhy_idx[b] = am;
}

// ---------------------------------------------------------------------------
// melody softmax: 130 classes from 8 partial slots (stride 16384), argmax fb
// ---------------------------------------------------------------------------
__global__ __launch_bounds__(256) void mel_smax(
    const float* __restrict__ part, const float* __restrict__ bo1,
    float* __restrict__ outp, int t, int* __restrict__ mel_idx)
{
    int b = blockIdx.x, tid = threadIdx.x;
    float v = -1e30f;
    if (tid < MELn) {
        v = bo1[tid];
#pragma unroll
        for (int s = 0; s < 8; s++) v += part[s * 16384 + tid * 64 + b];
    }
    __shared__ float smax[256];
    __shared__ int   sidx[256];
    __shared__ float ssum[256];
    smax[tid] = v; sidx[tid] = tid;
    __syncthreads();
    for (int s = 128; s > 0; s >>= 1) {
        if (tid < s) {
            float a = smax[tid], o = smax[tid + s];
            int ai = sidx[tid], oi = sidx[tid + s];
            if (o > a || (o == a && oi < ai)) { smax[tid] = o; sidx[tid] = oi; }
        }
        __syncthreads();
    }
    float mx = smax[0]; int am = sidx[0];
    ssum[tid] = (tid < MELn) ? expf(v - mx) : 0.f;
    __syncthreads();
    for (int s = 128; s > 0; s >>= 1) {
        if (tid < s) ssum[tid] += ssum[tid + s];
        __syncthreads();
    }
    float ls = logf(ssum[0]);
    if (tid < MELn) outp[(size_t)b * Tn * MELn + t * MELn + tid] = v - mx - ls;
    if (tid == 0) mel_idx[b] = am;
}

// ---------------------------------------------------------------------------
extern "C" void kernel_launch(void* const* d_in, const int* in_sizes, int n_in,
                              void* d_out, int out_size, void* d_ws, size_t ws_size,
                              hipStream_t stream)
{
    (void)in_sizes; (void)n_in; (void)out_size; (void)ws_size;
    const float* z1    = (const float*)d_in[0];
    const float* z2    = (const float*)d_in[1];
    const float* cond  = (const float*)d_in[2];
    const float* w_ih0 = (const float*)d_in[3];
    const float* w_hh0 = (const float*)d_in[4];
    const float* b_ih0 = (const float*)d_in[5];
    const float* b_hh0 = (const float*)d_in[6];
    const float* w_ih1 = (const float*)d_in[7];
    const float* w_hh1 = (const float*)d_in[8];
    const float* b_ih1 = (const float*)d_in[9];
    const float* b_hh1 = (const float*)d_in[10];
    const float* w_ih2 = (const float*)d_in[11];
    const float* w_hh2 = (const float*)d_in[12];
    const float* b_ih2 = (const float*)d_in[13];
    const float* b_hh2 = (const float*)d_in[14];
    const float* wi0   = (const float*)d_in[15];
    const float* bi0   = (const float*)d_in[16];
    const float* wo0   = (const float*)d_in[17];
    const float* bo0   = (const float*)d_in[18];
    const float* wi1   = (const float*)d_in[19];
    const float* bi1   = (const float*)d_in[20];
    const float* wo1   = (const float*)d_in[21];
    const float* bo1   = (const float*)d_in[22];
    float* outp = (float*)d_out;
    float* ws = (float*)d_ws;

    // workspace layout (floats), total ~58.5M floats = 234 MB
    size_t off = 0;
    float* WT0  = ws + off; off += 12582912;   // w_hh0^T [2048][6144]
    float* WT1  = ws + off; off += 12582912;   // w_hh1^T
    float* WTi2 = ws + off; off += 12582912;   // w_ih2^T
    float* WTh2 = ws + off; off += 12582912;   // w_hh2^T
    float* WTo1 = ws + off; off += 266240;     // wo1^T [2048][130]
    float* WTo0 = ws + off; off += 6144;       // wo0^T [2048][3]
    float* part = ws + off; off += 6291456;    // k-split partials (25 MB)
    float* hR[2] = { ws + off, ws + off + 131072 }; off += 262144;
    float* hA[2] = { ws + off, ws + off + 131072 }; off += 262144;
    float* hB[2] = { ws + off, ws + off + 131072 }; off += 262144;
    float* gi0c   = ws + off; off += 393216;
    float* gi1c   = ws + off; off += 393216;
    float* rlo    = ws + off; off += 6144;     // [32][64][3]
    float* cond_t = ws + off; off += 24576;
    float* z1t    = ws + off; off += 8192;
    float* z2t    = ws + off; off += 8192;
    int* rhy_idx  = (int*)(ws + off); off += 64;
    int* mel_idx  = (int*)(ws + off); off += 64;

    // ---- pre-pass ----
    prep_misc<<<96, 256, 0, stream>>>(z1, z2, cond, z1t, z2t, cond_t, rhy_idx, mel_idx);
    init_h_k<<<dim3(Hd / 4, 2), 256, 0, stream>>>(z1t, z2t, wi0, bi0, wi1, bi1, hR[0], hA[0]);
    gi_const_k<<<dim3(G3 / 4, 2), 256, 0, stream>>>(z1t, z2t, w_ih0, b_ih0, w_ih1, b_ih1, gi0c, gi1c);
    transpose4_k<<<dim3(32, 96, 4), 256, 0, stream>>>(w_hh0, w_hh1, w_ih2, w_hh2,
                                                      WT0, WT1, WTi2, WTh2);
    transpose1_k<<<dim3(32, 3), 256, 0, stream>>>(wo1, WTo1, MELn, Hd);
    transpose1_k<<<dim3(32, 1), 256, 0, stream>>>(wo0, WTo0, RHYn, Hd);

    // ---- rhythm decoder ----
    for (int s = 0; s < Tn; s++) {
        const float* h_in = hR[s & 1];
        float* h_out = hR[(s + 1) & 1];
        mm_k<<<dim3(48, 16, 2), 128, 0, stream>>>(WT0, h_in, WT0, h_in, part,
                                                  G3, G3, 48, 128, 393216);
        rhy_epi<<<512, 256, 0, stream>>>(part, gi0c, w_ih0, b_hh0, h_in, h_out, rhy_idx);
        mm_k<<<dim3(1, 8, 2), 128, 0, stream>>>(WTo0, h_out, WTo0, h_out, part,
                                                RHYn, RHYn, 1, 256, 8192);
        rhy_smax<<<1, 64, 0, stream>>>(part, bo0, rlo + s * 192, rhy_idx);
    }

    // ---- melody decoder ----
    for (int t = 0; t < Tn; t++) {
        const float* ha_in = hA[t & 1];
        float* ha_out = hA[(t + 1) & 1];
        mm_k<<<dim3(48, 16, 2), 128, 0, stream>>>(WT1, ha_in, WT1, ha_in, part,
                                                  G3, G3, 48, 128, 393216);
        mel1_epi<<<512, 256, 0, stream>>>(part, gi1c, w_ih1, b_hh1, ha_in, ha_out,
                                          mel_idx, rlo + t * 192, cond_t + t * (CHn * Bsz));
        const float* hb_in = (t == 0) ? (const float*)ha_out : (const float*)hB[t & 1];
        float* hb_out = hB[(t + 1) & 1];
        mm_k<<<dim3(96, 8, 2), 128, 0, stream>>>(WTi2, ha_out, WTh2, hb_in, part,
                                                 G3, G3, 48, 256, 786432);
        mel2_epi<<<512, 256, 0, stream>>>(part, b_ih2, b_hh2, hb_in, hb_out);
        mm_k<<<dim3(2, 8, 2), 128, 0, stream>>>(WTo1, hb_out, WTo1, hb_out, part,
                                                MELn, MELn, 2, 256, 16384);
        mel_smax<<<Bsz, 256, 0, stream>>>(part, bo1, outp, t, mel_idx);
    }
}

// Round 3
// 9621.008 us; speedup vs baseline: 1.5891x; 1.2275x over previous
//
#include <hip/hip_runtime.h>
#include <hip/hip_bf16.h>
#include <math.h>

#define Bsz  64
#define Hd   2048
#define G3   6144
#define MELn 130
#define CHn  12
#define RHYn 3
#define Tn   32

__device__ __forceinline__ float sigf(float x) { return 1.0f / (1.0f + expf(-x)); }

// ---------------------------------------------------------------------------
// prep: transpose z1/z2 -> [128][64], condition -> [T][CH][64], init feedback idx
// ---------------------------------------------------------------------------
__global__ void prep_misc(const float* __restrict__ z1, const float* __restrict__ z2,
                          const float* __restrict__ cond,
                          float* __restrict__ z1t, float* __restrict__ z2t,
                          float* __restrict__ cond_t, int* __restrict__ rhy_idx,
                          int* __restrict__ mel_idx)
{
    int idx = blockIdx.x * 256 + threadIdx.x;
    if (idx < 128 * Bsz) {
        int j = idx >> 6, b = idx & 63;
        z1t[idx] = z1[b * 128 + j];
        z2t[idx] = z2[b * 128 + j];
    }
    if (idx < Tn * CHn * Bsz) {
        int t = idx / (CHn * Bsz);
        int r = idx - t * CHn * Bsz;
        int j = r >> 6, b = r & 63;
        cond_t[idx] = cond[b * (Tn * CHn) + t * CHn + j];
    }
    if (idx < Bsz) { rhy_idx[idx] = RHYn - 1; mel_idx[idx] = MELn - 1; }
}

// ---------------------------------------------------------------------------
// h0 = tanh(z2 @ wi0.T + bi0), h1 = tanh(z1 @ wi1.T + bi1); output [j][b]
// ---------------------------------------------------------------------------
__global__ __launch_bounds__(256) void init_h_k(
    const float* __restrict__ z1t, const float* __restrict__ z2t,
    const float* __restrict__ wi0, const float* __restrict__ bi0,
    const float* __restrict__ wi1, const float* __restrict__ bi1,
    float* __restrict__ h0_out, float* __restrict__ h1_out)
{
    int lane = threadIdx.x & 63, wave = threadIdx.x >> 6;
    int j = blockIdx.x * 4 + wave;
    int which = blockIdx.y;
    const float* zt = which ? z1t : z2t;
    const float* wi = which ? wi1 : wi0;
    const float* bi = which ? bi1 : bi0;
    float* outh = which ? h1_out : h0_out;
    const float4* w4 = (const float4*)(wi + (size_t)j * 128);
    float acc = 0.f;
#pragma unroll 8
    for (int i = 0; i < 32; i++) {
        float4 w = w4[i];
        int k = i * 4;
        acc = fmaf(zt[(k + 0) * 64 + lane], w.x, acc);
        acc = fmaf(zt[(k + 1) * 64 + lane], w.y, acc);
        acc = fmaf(zt[(k + 2) * 64 + lane], w.z, acc);
        acc = fmaf(zt[(k + 3) * 64 + lane], w.w, acc);
    }
    outh[j * 64 + lane] = tanhf(acc + bi[j]);
}

// ---------------------------------------------------------------------------
// step-invariant ih parts (z-terms + bias), layout [row][64]
// ---------------------------------------------------------------------------
__global__ __launch_bounds__(256) void gi_const_k(
    const float* __restrict__ z1t, const float* __restrict__ z2t,
    const float* __restrict__ w_ih0, const float* __restrict__ b_ih0,
    const float* __restrict__ w_ih1, const float* __restrict__ b_ih1,
    float* __restrict__ gi0c, float* __restrict__ gi1c)
{
    int lane = threadIdx.x & 63, wave = threadIdx.x >> 6;
    int row = blockIdx.x * 4 + wave;
    int which = blockIdx.y;
    const float* zt; const float* w; float acc; float* dst;
    if (which == 0) { zt = z2t; w = w_ih0 + (size_t)row * 131 + RHYn;          acc = b_ih0[row]; dst = gi0c; }
    else            { zt = z1t; w = w_ih1 + (size_t)row * 273 + (MELn + RHYn); acc = b_ih1[row]; dst = gi1c; }
#pragma unroll 4
    for (int i = 0; i < 128; i++) acc = fmaf(zt[i * 64 + lane], w[i], acc);
    dst[(size_t)row * 64 + lane] = acc;
}

// ---------------------------------------------------------------------------
// 64x64 tile transpose: in [R][C] -> out [C][Rout] (Rout >= R allows padding)
// ---------------------------------------------------------------------------
__device__ __forceinline__ void transpose_body(
    const float* __restrict__ in, float* __restrict__ out, int R, int C, int Rout,
    int bx, int by, float* tile)
{
    int c0 = bx * 64, r0 = by * 64;
    int t = threadIdx.x;
    int cl = t & 63, rw = t >> 6;
#pragma unroll
    for (int i = 0; i < 16; ++i) {
        int rl = rw + i * 4;
        int r = r0 + rl, c = c0 + cl;
        float v = (r < R && c < C) ? in[(size_t)r * C + c] : 0.f;
        tile[rl * 65 + cl] = v;
    }
    __syncthreads();
#pragma unroll
    for (int i = 0; i < 16; ++i) {
        int c_loc = rw + i * 4;
        int r_loc = cl;
        int oc = c0 + c_loc, orow = r0 + r_loc;
        if (oc < C && orow < R)
            out[(size_t)oc * Rout + orow] = tile[r_loc * 65 + c_loc];
    }
}

__global__ __launch_bounds__(256) void transpose4_k(
    const float* __restrict__ a, const float* __restrict__ b,
    const float* __restrict__ c, const float* __restrict__ d,
    float* __restrict__ oa, float* __restrict__ ob,
    float* __restrict__ oc, float* __restrict__ od)
{
    __shared__ float tile[64 * 65];
    const float* in; float* out;
    switch (blockIdx.z) {
        case 0: in = a; out = oa; break;
        case 1: in = b; out = ob; break;
        case 2: in = c; out = oc; break;
        default: in = d; out = od; break;
    }
    transpose_body(in, out, G3, Hd, G3, blockIdx.x, blockIdx.y, tile);
}

__global__ __launch_bounds__(256) void transpose1_k(
    const float* __restrict__ in, float* __restrict__ out, int R, int C, int Rout)
{
    __shared__ float tile[64 * 65];
    transpose_body(in, out, R, C, Rout, blockIdx.x, blockIdx.y, tile);
}

// ---------------------------------------------------------------------------
// mm2_k: register-tiled k-split GEMM partial.
// Block 256 thr, tile 128 rows x 64 batch, thread 8r x 4b.
// grid (tiles, slots). part[slot][prow][b] = sum_{k in chunk} WT[k][row]*x[k][b]
// Fused two-matrix mode: tiles >= splitTile use (WTb, xb); part rows continue.
// ---------------------------------------------------------------------------
__global__ __launch_bounds__(256) void mm2_k(
    const float* __restrict__ WTa, const float* __restrict__ xa,
    const float* __restrict__ WTb, const float* __restrict__ xb,
    float* __restrict__ part, int splitTile, int kc, int nrows, int wstride,
    int partStride)
{
    __shared__ float xs[128 * 64];
    int tid = threadIdx.x;
    int tile = blockIdx.x, slot = blockIdx.y;
    const float* WT; const float* x; int tLoc;
    if (tile < splitTile) { WT = WTa; x = xa; tLoc = tile; }
    else                  { WT = WTb; x = xb; tLoc = tile - splitTile; }
    int rg = tid & 15, bg = tid >> 4;
    int r0 = tLoc * 128 + rg * 8;
    int b0 = bg * 4;
    int k0 = slot * kc;

    float acc[8][4];
#pragma unroll
    for (int i = 0; i < 8; i++)
#pragma unroll
        for (int j = 0; j < 4; j++) acc[i][j] = 0.f;

    bool fast = (r0 + 7 < nrows);
    int nPhase = kc >> 7;
    for (int ph = 0; ph < nPhase; ++ph) {
        int kp = k0 + ph * 128;
        __syncthreads();
        {
            const float4* src = (const float4*)(x + (size_t)kp * 64);
            float4* dst = (float4*)xs;
#pragma unroll
            for (int i = 0; i < 8; i++) dst[tid + i * 256] = src[tid + i * 256];
        }
        __syncthreads();
        if (fast) {
            const float* wp = WT + (size_t)kp * wstride + r0;
#pragma unroll 4
            for (int k = 0; k < 128; ++k) {
                float4 xv = *(const float4*)&xs[k * 64 + b0];
                float w[8];
                *(float4*)&w[0] = *(const float4*)wp;
                *(float4*)&w[4] = *(const float4*)(wp + 4);
                wp += wstride;
#pragma unroll
                for (int i = 0; i < 8; i++) {
                    acc[i][0] = fmaf(w[i], xv.x, acc[i][0]);
                    acc[i][1] = fmaf(w[i], xv.y, acc[i][1]);
                    acc[i][2] = fmaf(w[i], xv.z, acc[i][2]);
                    acc[i][3] = fmaf(w[i], xv.w, acc[i][3]);
                }
            }
        } else {
            for (int k = 0; k < 128; ++k) {
                float4 xv = *(const float4*)&xs[k * 64 + b0];
                const float* wrow = WT + (size_t)(kp + k) * wstride;
                float w[8];
#pragma unroll
                for (int i = 0; i < 8; i++) {
                    int rc = r0 + i; if (rc > nrows - 1) rc = nrows - 1;
                    w[i] = wrow[rc];
                }
#pragma unroll
                for (int i = 0; i < 8; i++) {
                    acc[i][0] = fmaf(w[i], xv.x, acc[i][0]);
                    acc[i][1] = fmaf(w[i], xv.y, acc[i][1]);
                    acc[i][2] = fmaf(w[i], xv.z, acc[i][2]);
                    acc[i][3] = fmaf(w[i], xv.w, acc[i][3]);
                }
            }
        }
    }

    size_t base = (size_t)slot * partStride + b0;
#pragma unroll
    for (int i = 0; i < 8; i++) {
        int prow = tile * 128 + rg * 8 + i;
        int pc = prow < nrows ? prow : (nrows - 1);
        // tiles in fused mode continue past nrows of matrix A; recompute for B
        if (tile >= splitTile) pc = prow;   // big fused mats never clamp
        *(float4*)&part[base + (size_t)pc * 64] = *(float4*)acc[i];
    }
}

// ---------------------------------------------------------------------------
// rhythm epilogue: sum 16 k-slots, gate math, h'
// ---------------------------------------------------------------------------
__global__ __launch_bounds__(256) void rhy_epi(
    const float* __restrict__ part, const float* __restrict__ gi_c,
    const float* __restrict__ w_ih, const float* __restrict__ b_hh,
    const float* __restrict__ h_in, float* __restrict__ h_out,
    const int* __restrict__ fb_idx)
{
    int tid = threadIdx.x;
    int b = tid & 63, jw = tid >> 6;
    int j = blockIdx.x * 4 + jw;
    float ar = 0.f, az = 0.f, an = 0.f;
#pragma unroll
    for (int s = 0; s < 16; s++) {
        int sb = s * 393216;
        ar += part[sb + j * 64 + b];
        az += part[sb + (j + 2048) * 64 + b];
        an += part[sb + (j + 4096) * 64 + b];
    }
    int oi = fb_idx[b];
    float gir = gi_c[j * 64 + b]            + w_ih[(size_t)j * 131 + oi];
    float giz = gi_c[(j + 2048) * 64 + b]   + w_ih[(size_t)(j + 2048) * 131 + oi];
    float gin = gi_c[(j + 4096) * 64 + b]   + w_ih[(size_t)(j + 4096) * 131 + oi];
    float rg = sigf(gir + ar + b_hh[j]);
    float ug = sigf(giz + az + b_hh[j + 2048]);
    float ng = tanhf(gin + rg * (an + b_hh[j + 4096]));
    float hp = h_in[j * 64 + b];
    h_out[j * 64 + b] = (1.f - ug) * ng + ug * hp;
}

// ---------------------------------------------------------------------------
// fused rhythm logits (3 classes) + log_softmax + argmax; 1 block, 768 thr
// ---------------------------------------------------------------------------
__global__ __launch_bounds__(768) void rhy_out_k(
    const float* __restrict__ h, const float* __restrict__ wo0,
    const float* __restrict__ bo0, float* __restrict__ rlo_t, int* __restrict__ rhy_idx)
{
    __shared__ float partl[12 * 64];
    int tid = threadIdx.x, lane = tid & 63, wave = tid >> 6;
    int c = wave >> 2, chunk = wave & 3;
    const float* w = wo0 + c * Hd + chunk * 512;
    const float* hc = h + chunk * 512 * 64;
    float acc = 0.f;
#pragma unroll 4
    for (int k = 0; k < 512; k++) acc = fmaf(hc[k * 64 + lane], w[k], acc);
    partl[wave * 64 + lane] = acc;
    __syncthreads();
    if (wave == 0) {
        float l0 = partl[0 * 64 + lane] + partl[1 * 64 + lane] + partl[2 * 64 + lane] + partl[3 * 64 + lane] + bo0[0];
        float l1 = partl[4 * 64 + lane] + partl[5 * 64 + lane] + partl[6 * 64 + lane] + partl[7 * 64 + lane] + bo0[1];
        float l2 = partl[8 * 64 + lane] + partl[9 * 64 + lane] + partl[10 * 64 + lane] + partl[11 * 64 + lane] + bo0[2];
        int am; float mx;
        if (l0 >= l1 && l0 >= l2) { am = 0; mx = l0; }
        else if (l1 >= l2)        { am = 1; mx = l1; }
        else                      { am = 2; mx = l2; }
        float s = expf(l0 - mx) + expf(l1 - mx) + expf(l2 - mx);
        float ls = logf(s);
        rlo_t[lane * 3 + 0] = l0 - mx - ls;
        rlo_t[lane * 3 + 1] = l1 - mx - ls;
        rlo_t[lane * 3 + 2] = l2 - mx - ls;
        rhy_idx[lane] = am;
    }
}

// ---------------------------------------------------------------------------
// melody GRU1 epilogue: sum 16 slots + one-hot col + rank-15 corrections
// ---------------------------------------------------------------------------
__global__ __launch_bounds__(256) void mel1_epi(
    const float* __restrict__ part, const float* __restrict__ gi_c,
    const float* __restrict__ w_ih, const float* __restrict__ b_hh,
    const float* __restrict__ h_in, float* __restrict__ h_out,
    const int* __restrict__ mel_idx, const float* __restrict__ rlo,
    const float* __restrict__ cdt)
{
    int tid = threadIdx.x;
    int b = tid & 63, jw = tid >> 6;
    int j = blockIdx.x * 4 + jw;
    float ar = 0.f, az = 0.f, an = 0.f;
#pragma unroll
    for (int s = 0; s < 16; s++) {
        int sb = s * 393216;
        ar += part[sb + j * 64 + b];
        az += part[sb + (j + 2048) * 64 + b];
        an += part[sb + (j + 4096) * 64 + b];
    }
    int oi = mel_idx[b];
    float r0 = rlo[b * 3 + 0], r1 = rlo[b * 3 + 1], r2 = rlo[b * 3 + 2];
    float cd[12];
#pragma unroll
    for (int q = 0; q < 12; q++) cd[q] = cdt[q * 64 + b];
    float gi[3];
#pragma unroll
    for (int g = 0; g < 3; g++) {
        int row = j + g * 2048;
        const float* wrow = w_ih + (size_t)row * 273;
        float v = gi_c[row * 64 + b] + wrow[oi];
        v = fmaf(r0, wrow[130], v);
        v = fmaf(r1, wrow[131], v);
        v = fmaf(r2, wrow[132], v);
#pragma unroll
        for (int q = 0; q < 12; q++) v = fmaf(cd[q], wrow[261 + q], v);
        gi[g] = v;
    }
    float rg = sigf(gi[0] + ar + b_hh[j]);
    float ug = sigf(gi[1] + az + b_hh[j + 2048]);
    float ng = tanhf(gi[2] + rg * (an + b_hh[j + 4096]));
    float hp = h_in[j * 64 + b];
    h_out[j * 64 + b] = (1.f - ug) * ng + ug * hp;
}

// ---------------------------------------------------------------------------
// melody GRU2 epilogue: fused rows [0,6144)=gi (ih2 x ha'), [6144,12288)=gh
// ---------------------------------------------------------------------------
__global__ __launch_bounds__(256) void mel2_epi(
    const float* __restrict__ part, const float* __restrict__ b_ih,
    const float* __restrict__ b_hh, const float* __restrict__ hb_in,
    float* __restrict__ hb_out)
{
    int tid = threadIdx.x;
    int b = tid & 63, jw = tid >> 6;
    int j = blockIdx.x * 4 + jw;
    float air = 0.f, aiz = 0.f, ain = 0.f, ahr = 0.f, ahz = 0.f, ahn = 0.f;
#pragma unroll
    for (int s = 0; s < 8; s++) {
        int sb = s * 786432;
        air += part[sb + j * 64 + b];
        aiz += part[sb + (j + 2048) * 64 + b];
        ain += part[sb + (j + 4096) * 64 + b];
        ahr += part[sb + (j + 6144) * 64 + b];
        ahz += part[sb + (j + 8192) * 64 + b];
        ahn += part[sb + (j + 10240) * 64 + b];
    }
    float rg = sigf(air + b_ih[j] + ahr + b_hh[j]);
    float ug = sigf(aiz + b_ih[j + 2048] + ahz + b_hh[j + 2048]);
    float ng = tanhf(ain + b_ih[j + 4096] + rg * (ahn + b_hh[j + 4096]));
    float hp = hb_in[j * 64 + b];
    hb_out[j * 64 + b] = (1.f - ug) * ng + ug * hp;
}

// ---------------------------------------------------------------------------
// melody softmax: 130 classes from 16 partial slots (stride 8320), argmax fb
// ---------------------------------------------------------------------------
__global__ __launch_bounds__(256) void mel_smax(
    const float* __restrict__ part, const float* __restrict__ bo1,
    float* __restrict__ outp, int t, int* __restrict__ mel_idx)
{
    int b = blockIdx.x, tid = threadIdx.x;
    float v = -1e30f;
    if (tid < MELn) {
        v = bo1[tid];
#pragma unroll
        for (int s = 0; s < 16; s++) v += part[s * 8320 + tid * 64 + b];
    }
    __shared__ float smax[256];
    __shared__ int   sidx[256];
    __shared__ float ssum[256];
    smax[tid] = v; sidx[tid] = tid;
    __syncthreads();
    for (int s = 128; s > 0; s >>= 1) {
        if (tid < s) {
            float a = smax[tid], o = smax[tid + s];
            int ai = sidx[tid], oi = sidx[tid + s];
            if (o > a || (o == a && oi < ai)) { smax[tid] = o; sidx[tid] = oi; }
        }
        __syncthreads();
    }
    float mx = smax[0]; int am = sidx[0];
    ssum[tid] = (tid < MELn) ? expf(v - mx) : 0.f;
    __syncthreads();
    for (int s = 128; s > 0; s >>= 1) {
        if (tid < s) ssum[tid] += ssum[tid + s];
        __syncthreads();
    }
    float ls = logf(ssum[0]);
    if (tid < MELn) outp[(size_t)b * Tn * MELn + t * MELn + tid] = v - mx - ls;
    if (tid == 0) mel_idx[b] = am;
}

// ---------------------------------------------------------------------------
extern "C" void kernel_launch(void* const* d_in, const int* in_sizes, int n_in,
                              void* d_out, int out_size, void* d_ws, size_t ws_size,
                              hipStream_t stream)
{
    (void)in_sizes; (void)n_in; (void)out_size; (void)ws_size;
    const float* z1    = (const float*)d_in[0];
    const float* z2    = (const float*)d_in[1];
    const float* cond  = (const float*)d_in[2];
    const float* w_ih0 = (const float*)d_in[3];
    const float* w_hh0 = (const float*)d_in[4];
    const float* b_ih0 = (const float*)d_in[5];
    const float* b_hh0 = (const float*)d_in[6];
    const float* w_ih1 = (const float*)d_in[7];
    const float* w_hh1 = (const float*)d_in[8];
    const float* b_ih1 = (const float*)d_in[9];
    const float* b_hh1 = (const float*)d_in[10];
    const float* w_ih2 = (const float*)d_in[11];
    const float* w_hh2 = (const float*)d_in[12];
    const float* b_ih2 = (const float*)d_in[13];
    const float* b_hh2 = (const float*)d_in[14];
    const float* wi0   = (const float*)d_in[15];
    const float* bi0   = (const float*)d_in[16];
    const float* wo0   = (const float*)d_in[17];
    const float* bo0   = (const float*)d_in[18];
    const float* wi1   = (const float*)d_in[19];
    const float* bi1   = (const float*)d_in[20];
    const float* wo1   = (const float*)d_in[21];
    const float* bo1   = (const float*)d_in[22];
    float* outp = (float*)d_out;
    float* ws = (float*)d_ws;

    // workspace layout (floats), ~232 MB
    size_t off = 0;
    float* WT0  = ws + off; off += 12582912;   // w_hh0^T [2048][6144]
    float* WT1  = ws + off; off += 12582912;   // w_hh1^T
    float* WTi2 = ws + off; off += 12582912;   // w_ih2^T
    float* WTh2 = ws + off; off += 12582912;   // w_hh2^T
    float* WTo1 = ws + off; off += 270336;     // wo1^T [2048][132] (padded)
    float* part = ws + off; off += 6291456;    // k-split partials (25 MB)
    float* hR[2] = { ws + off, ws + off + 131072 }; off += 262144;
    float* hA[2] = { ws + off, ws + off + 131072 }; off += 262144;
    float* hB[2] = { ws + off, ws + off + 131072 }; off += 262144;
    float* gi0c   = ws + off; off += 393216;
    float* gi1c   = ws + off; off += 393216;
    float* rlo    = ws + off; off += 6144;     // [32][64][3]
    float* cond_t = ws + off; off += 24576;
    float* z1t    = ws + off; off += 8192;
    float* z2t    = ws + off; off += 8192;
    int* rhy_idx  = (int*)(ws + off); off += 64;
    int* mel_idx  = (int*)(ws + off); off += 64;

    // ---- pre-pass ----
    prep_misc<<<96, 256, 0, stream>>>(z1, z2, cond, z1t, z2t, cond_t, rhy_idx, mel_idx);
    init_h_k<<<dim3(Hd / 4, 2), 256, 0, stream>>>(z1t, z2t, wi0, bi0, wi1, bi1, hR[0], hA[0]);
    gi_const_k<<<dim3(G3 / 4, 2), 256, 0, stream>>>(z1t, z2t, w_ih0, b_ih0, w_ih1, b_ih1, gi0c, gi1c);
    transpose4_k<<<dim3(32, 96, 4), 256, 0, stream>>>(w_hh0, w_hh1, w_ih2, w_hh2,
                                                      WT0, WT1, WTi2, WTh2);
    transpose1_k<<<dim3(32, 3), 256, 0, stream>>>(wo1, WTo1, MELn, Hd, 132);

    // ---- rhythm decoder ----
    for (int s = 0; s < Tn; s++) {
        const float* h_in = hR[s & 1];
        float* h_out = hR[(s + 1) & 1];
        mm2_k<<<dim3(48, 16), 256, 0, stream>>>(WT0, h_in, WT0, h_in, part,
                                                48, 128, G3, G3, 393216);
        rhy_epi<<<512, 256, 0, stream>>>(part, gi0c, w_ih0, b_hh0, h_in, h_out, rhy_idx);
        rhy_out_k<<<1, 768, 0, stream>>>(h_out, wo0, bo0, rlo + s * 192, rhy_idx);
    }

    // ---- melody decoder ----
    for (int t = 0; t < Tn; t++) {
        const float* ha_in = hA[t & 1];
        float* ha_out = hA[(t + 1) & 1];
        mm2_k<<<dim3(48, 16), 256, 0, stream>>>(WT1, ha_in, WT1, ha_in, part,
                                                48, 128, G3, G3, 393216);
        mel1_epi<<<512, 256, 0, stream>>>(part, gi1c, w_ih1, b_hh1, ha_in, ha_out,
                                          mel_idx, rlo + t * 192, cond_t + t * (CHn * Bsz));
        const float* hb_in = (t == 0) ? (const float*)ha_out : (const float*)hB[t & 1];
        float* hb_out = hB[(t + 1) & 1];
        mm2_k<<<dim3(96, 8), 256, 0, stream>>>(WTi2, ha_out, WTh2, hb_in, part,
                                               48, 256, G3, G3, 786432);
        mel2_epi<<<512, 256, 0, stream>>>(part, b_ih2, b_hh2, hb_in, hb_out);
        mm2_k<<<dim3(2, 16), 256, 0, stream>>>(WTo1, hb_out, WTo1, hb_out, part,
                                               2, 128, MELn, 132, 8320);
        mel_smax<<<Bsz, 256, 0, stream>>>(part, bo1, outp, t, mel_idx);
    }
}